// Round 3
// baseline (472.652 us; speedup 1.0000x reference)
//
#include <hip/hip_runtime.h>

#define THREADS 256
#define SCAN_ITEMS 8    // 2048 elements per scan block
#define NSB 128         // sort blocks: run length E/NSB = 12500 edges
#define BKT_MAX 3200    // >= ceil(N/32)

typedef float f32x4 __attribute__((ext_vector_type(4)));
typedef __bf16 bf16x8 __attribute__((ext_vector_type(8)));
typedef int intx4 __attribute__((ext_vector_type(4)));

__device__ inline unsigned short f32_to_bf16_rne(float f) {
    unsigned int u = __float_as_uint(f);
    unsigned int r = u + 0x7fffu + ((u >> 16) & 1u);
    return (unsigned short)(r >> 16);
}
__device__ inline float bf16_bits_to_f32(unsigned short h) {
    return __uint_as_float(((unsigned int)h) << 16);
}
__device__ inline uint4 pack8(const unsigned short* s) {
    uint4 u;
    u.x = (unsigned int)s[0] | ((unsigned int)s[1] << 16);
    u.y = (unsigned int)s[2] | ((unsigned int)s[3] << 16);
    u.z = (unsigned int)s[4] | ((unsigned int)s[5] << 16);
    u.w = (unsigned int)s[6] | ((unsigned int)s[7] << 16);
    return u;
}

__global__ void zero_kernel(int* __restrict__ p, int n) {
    int i = blockIdx.x * 256 + threadIdx.x;
    if (i < n) p[i] = 0;
}

// ---------------- coarse counting sort (32-node buckets) ----------------
// Also builds the per-node histogram (global atomics, L2-resident 400KB).
__global__ __launch_bounds__(256) void hist32(const int* __restrict__ dst,
                                              int* __restrict__ hist,
                                              int* __restrict__ nodecnt,
                                              int E, int nbkt, int chunk) {
    __shared__ int lh[BKT_MAX];
    const int tid = threadIdx.x, blk = blockIdx.x;
    for (int i = tid; i < nbkt; i += 256) lh[i] = 0;
    __syncthreads();
    int s = blk * chunk, e = s + chunk; if (e > E) e = E;
    if (((size_t)dst & 15) == 0) {
        int n4 = (e > s) ? ((e - s) >> 2) : 0;
        const intx4* d4p = (const intx4*)(dst + s);
        for (int i = tid; i < n4; i += 256) {
            intx4 d4 = d4p[i];
#pragma unroll
            for (int k = 0; k < 4; k++) {
                atomicAdd(&lh[d4[k] >> 5], 1);
                atomicAdd(&nodecnt[d4[k]], 1);
            }
        }
        for (int j = s + (n4 << 2) + tid; j < e; j += 256) {
            atomicAdd(&lh[dst[j] >> 5], 1);
            atomicAdd(&nodecnt[dst[j]], 1);
        }
    } else {
        for (int j = s + tid; j < e; j += 256) {
            atomicAdd(&lh[dst[j] >> 5], 1);
            atomicAdd(&nodecnt[dst[j]], 1);
        }
    }
    __syncthreads();
    for (int i = tid; i < nbkt; i += 256) hist[i * NSB + blk] = lh[i];
}

__global__ void scan1_kernel(const int* __restrict__ cnt, int* __restrict__ off,
                             int* __restrict__ bsums, int n) {
    __shared__ int sdata[THREADS];
    int base = blockIdx.x * (THREADS * SCAN_ITEMS) + threadIdx.x * SCAN_ITEMS;
    int vals[SCAN_ITEMS];
    int tsum = 0;
#pragma unroll
    for (int k = 0; k < SCAN_ITEMS; k++) {
        int idx = base + k;
        int v = (idx < n) ? cnt[idx] : 0;
        vals[k] = tsum;
        tsum += v;
    }
    sdata[threadIdx.x] = tsum;
    __syncthreads();
    for (int s = 1; s < THREADS; s <<= 1) {
        int y = (threadIdx.x >= (unsigned)s) ? sdata[threadIdx.x - s] : 0;
        __syncthreads();
        sdata[threadIdx.x] += y;
        __syncthreads();
    }
    int texcl = sdata[threadIdx.x] - tsum;
#pragma unroll
    for (int k = 0; k < SCAN_ITEMS; k++) {
        int idx = base + k;
        if (idx < n) off[idx] = texcl + vals[k];
    }
    if (threadIdx.x == THREADS - 1) bsums[blockIdx.x] = sdata[THREADS - 1];
}

__global__ void scan2_kernel(const int* __restrict__ bsums, int* __restrict__ bbase,
                             int nb, int* __restrict__ offN) {
    if (threadIdx.x == 0 && blockIdx.x == 0) {
        int run = 0;
        for (int i = 0; i < nb; i++) { bbase[i] = run; run += bsums[i]; }
        *offN = run;
    }
}

__global__ void scan3b_kernel(int* __restrict__ off, const int* __restrict__ bbase, int n) {
    int i = blockIdx.x * blockDim.x + threadIdx.x;
    if (i < n) off[i] += bbase[i >> 11];
}

// Pass 2: stable scatter into bucket-grouped array. Payload: src | dst_local<<17.
__global__ __launch_bounds__(256) void scatter32(const int* __restrict__ src,
                                                 const int* __restrict__ dst,
                                                 const int* __restrict__ hstS,
                                                 int* __restrict__ esrt,
                                                 int E, int nbkt, int chunk) {
    __shared__ int cur[BKT_MAX];
    const int tid = threadIdx.x, blk = blockIdx.x;
    for (int i = tid; i < nbkt; i += 256) cur[i] = hstS[i * NSB + blk];
    __syncthreads();
    int s = blk * chunk, e = s + chunk; if (e > E) e = E;
    if ((((size_t)dst | (size_t)src) & 15) == 0) {
        int n4 = (e > s) ? ((e - s) >> 2) : 0;
        const intx4* d4p = (const intx4*)(dst + s);
        const intx4* s4p = (const intx4*)(src + s);
        for (int i = tid; i < n4; i += 256) {
            intx4 d4 = d4p[i];
            intx4 s4 = s4p[i];
#pragma unroll
            for (int k = 0; k < 4; k++) {
                int d = d4[k];
                int p = atomicAdd(&cur[d >> 5], 1);
                esrt[p] = s4[k] | ((d & 31) << 17);
            }
        }
        for (int j = s + (n4 << 2) + tid; j < e; j += 256) {
            int d = dst[j];
            int p = atomicAdd(&cur[d >> 5], 1);
            esrt[p] = src[j] | ((d & 31) << 17);
        }
    } else {
        for (int j = s + tid; j < e; j += 256) {
            int d = dst[j];
            int p = atomicAdd(&cur[d >> 5], 1);
            esrt[p] = src[j] | ((d & 31) << 17);
        }
    }
}

// Pass 3: per-bucket node sort (single pass; per-node offsets precomputed).
__global__ __launch_bounds__(256) void sort2f(const int* __restrict__ esrt,
                                              const int* __restrict__ hstS,
                                              const int* __restrict__ noff,
                                              int* __restrict__ esrt2,
                                              int E, int nbkt) {
    __shared__ int cur[32];
    const int tid = threadIdx.x;
    const int b = blockIdx.x;
    const int p0 = hstS[b * NSB];
    const int p1 = (b + 1 < nbkt) ? hstS[(b + 1) * NSB] : E;
    if (tid < 32) cur[tid] = noff[b * 32 + tid];
    __syncthreads();
    for (int i = p0 + tid; i < p1; i += 256) {
        int pk = esrt[i];
        int p = atomicAdd(&cur[(pk >> 17) & 31], 1);
        esrt2[p] = pk;
    }
}

// ---------------- precision prep ----------------
__global__ void cvt_bf16_kernel(const float4* __restrict__ x, ushort4* __restrict__ o, int n4) {
    int i = blockIdx.x * blockDim.x + threadIdx.x;
    if (i < n4) {
        float4 v = x[i];
        ushort4 r;
        r.x = f32_to_bf16_rne(v.x);
        r.y = f32_to_bf16_rne(v.y);
        r.z = f32_to_bf16_rne(v.z);
        r.w = f32_to_bf16_rne(v.w);
        o[i] = r;
    }
}

// Swizzled hi/lo bf16 weights. W256[k][n]: k<128 -> Wn, else Wr.
__global__ void swizzle_w_kernel(const float* __restrict__ Wn, const float* __restrict__ Wr,
                                 uint4* __restrict__ out) {
    int id = blockIdx.x * blockDim.x + threadIdx.x;
    if (id >= 4096) return;
    int lane = id & 63;
    int nt = (id >> 6) & 7;
    int t = id >> 9;
    int kbase = t * 32 + (lane >> 4) * 8;
    int col = nt * 16 + (lane & 15);
    unsigned short hi[8], lo[8];
#pragma unroll
    for (int j = 0; j < 8; j++) {
        int k = kbase + j;
        const float* W = (k < 128) ? (Wn + (size_t)k * 128) : (Wr + (size_t)(k - 128) * 128);
        float v = W[col];
        unsigned short h = f32_to_bf16_rne(v);
        hi[j] = h;
        lo[j] = f32_to_bf16_rne(v - bf16_bits_to_f32(h));
    }
    out[(size_t)((t * 8 + nt) * 2 + 0) * 64 + lane] = pack8(hi);
    out[(size_t)((t * 8 + nt) * 2 + 1) * 64 + lane] = pack8(lo);
}

// ---------------- pure-gather aggregation, paired-edge loads ----------------
// Wave = 8 nodes' contiguous dst-sorted edge range. Lanes 0-31 handle even-
// slot edges, lanes 32-63 odd-slot edges; each lane loads 8B (4 dims) so one
// wave instruction moves 512B = 2 feature rows. 2-deep ping-pong of 8-pair
// batches keeps ~4KB/wave in flight during consume (2x R2). Halves keep
// separate 4-dim accumulators, merged with shfl_xor(32) at node flush.
// noff[node0..node0+8] preloaded to SGPRs: zero global loads in flush path.
__global__ __launch_bounds__(256) void agg_gather(const unsigned short* __restrict__ hb,
                                                  const int* __restrict__ esrt2,
                                                  const int* __restrict__ noff,
                                                  unsigned short* __restrict__ aggb,
                                                  int n) {
    const int tid = threadIdx.x, lane = tid & 63;
    const int w4 = __builtin_amdgcn_readfirstlane(tid >> 6);
    const int bucketBase = blockIdx.x * 32;
    const int node0 = bucketBase + w4 * 8;
    const int half = lane >> 5;     // 0: even-slot edges, 1: odd-slot edges
    const int l32 = lane & 31;      // dims 4*l32 .. 4*l32+3

    int no[9];
#pragma unroll
    for (int i = 0; i <= 8; i++) no[i] = noff[node0 + i];
    const int s = no[0], e2 = no[8];

    float a0 = 0.f, a1 = 0.f, a2 = 0.f, a3 = 0.f;
    int curL = 0;                   // local node index in [0,8]

    auto flushTo = [&](int tgt) {
        while (curL < tgt) {
            int node = node0 + curL;
            int d = no[curL + 1] - no[curL];
            float inv = 1.0f / (float)(d > 1 ? d : 1);
            float t0 = a0 + __shfl_xor(a0, 32);
            float t1 = a1 + __shfl_xor(a1, 32);
            float t2 = a2 + __shfl_xor(a2, 32);
            float t3 = a3 + __shfl_xor(a3, 32);
            if (half == 0 && node < n) {
                uint2 o;
                o.x = (unsigned int)f32_to_bf16_rne(t0 * inv)
                    | ((unsigned int)f32_to_bf16_rne(t1 * inv) << 16);
                o.y = (unsigned int)f32_to_bf16_rne(t2 * inv)
                    | ((unsigned int)f32_to_bf16_rne(t3 * inv) << 16);
                *(uint2*)(aggb + (size_t)node * 128 + l32 * 4) = o;
            }
            a0 = 0.f; a1 = 0.f; a2 = 0.f; a3 = 0.f;
            ++curL;
        }
    };
    auto loadK = [&](int* kv, int b) {
        int base = s + b * 16;
#pragma unroll
        for (int t = 0; t < 16; t++) {
            int idx = base + t;
            idx = (idx < e2) ? idx : (e2 - 1);
            kv[t] = esrt2[idx];                 // wave-uniform -> SGPR
        }
    };
    auto issueB = [&](uint2* V, const int* kv) {
#pragma unroll
        for (int j = 0; j < 8; j++) {
            int row = (half ? kv[2 * j + 1] : kv[2 * j]) & 0x1FFFF;
            V[j] = *(const uint2*)(hb + (size_t)row * 128 + l32 * 4);
        }
    };
    auto consumeB = [&](const uint2* V, const int* kv, int b) {
        int base = s + b * 16;
#pragma unroll
        for (int j = 0; j < 8; j++) {
            int e0 = base + 2 * j;
            if (e0 < e2) {
                flushTo(((kv[2 * j] >> 17) & 31) - w4 * 8);
                if (half == 0) {
                    uint2 v = V[j];
                    a0 += __uint_as_float(v.x << 16);
                    a1 += __uint_as_float(v.x & 0xffff0000u);
                    a2 += __uint_as_float(v.y << 16);
                    a3 += __uint_as_float(v.y & 0xffff0000u);
                }
            }
            int e1 = e0 + 1;
            if (e1 < e2) {
                flushTo(((kv[2 * j + 1] >> 17) & 31) - w4 * 8);
                if (half == 1) {
                    uint2 v = V[j];
                    a0 += __uint_as_float(v.x << 16);
                    a1 += __uint_as_float(v.x & 0xffff0000u);
                    a2 += __uint_as_float(v.y << 16);
                    a3 += __uint_as_float(v.y & 0xffff0000u);
                }
            }
        }
    };

    const int m = e2 - s;
    if (m > 0) {
        const int nbat = (m + 15) >> 4;
        int kvA[16], kvB[16];
        uint2 vA[8], vB[8];
        loadK(kvA, 0);
        issueB(vA, kvA);
        int k = 1;
        for (; k + 1 < nbat; k += 2) {
            loadK(kvB, k);
            issueB(vB, kvB);
            consumeB(vA, kvA, k - 1);
            loadK(kvA, k + 1);
            issueB(vA, kvA);
            consumeB(vB, kvB, k);
        }
        if (k < nbat) {
            loadK(kvB, k);
            issueB(vB, kvB);
            consumeB(vA, kvA, k - 1);
            consumeB(vB, kvB, k);
        } else {
            consumeB(vA, kvA, k - 1);
        }
    }
    flushTo(8);
}

// ---------------- fused SAGE update via split-bf16 MFMA ----------------
template <int LAYER, bool FINAL>
__global__ __launch_bounds__(256, 2) void update_mfma(
    const unsigned short* __restrict__ aggb, const void* __restrict__ hsrc,
    const uint4* __restrict__ Wsw, const float* __restrict__ bias,
    unsigned short* __restrict__ hout,
    const float* __restrict__ Wh, const float* __restrict__ bh,
    float* __restrict__ logits, int n) {
    __shared__ uint4 Alds[2048];
    __shared__ uint4 Wlds[2048];
    const int tid = threadIdx.x;
    const int lane = tid & 63;
    const int w = tid >> 6;
    const int i0 = blockIdx.x * 128;

    f32x4 acc[2][8];
#pragma unroll
    for (int mt = 0; mt < 2; mt++)
#pragma unroll
        for (int nt = 0; nt < 8; nt++) acc[mt][nt] = (f32x4)0.f;

    const int r = tid >> 1;
    const int half = tid & 1;
    const int rg = i0 + r;
    const bool inb = rg < n;
    const int mt_s = r >> 4;
    const int lidx = r & 15;

    for (int c = 0; c < 4; c++) {
        const bool haslo = (LAYER == 0 && c >= 2);
        {
            const uint4* srcW = Wsw + (size_t)c * 2048;
#pragma unroll
            for (int g = 0; g < 8; g++) Wlds[g * 256 + tid] = srcW[g * 256 + tid];
        }
        {
            unsigned short hiA[32], loA[32];
            if (LAYER == 0 && c >= 2) {
                const float4* s4 = (const float4*)((const float*)hsrc + (size_t)rg * 128 +
                                                   (c - 2) * 64 + half * 32);
#pragma unroll
                for (int q = 0; q < 8; q++) {
                    float4 f = inb ? s4[q] : make_float4(0.f, 0.f, 0.f, 0.f);
                    float vv[4] = {f.x, f.y, f.z, f.w};
#pragma unroll
                    for (int e = 0; e < 4; e++) {
                        unsigned short h = f32_to_bf16_rne(vv[e]);
                        hiA[q * 4 + e] = h;
                        loA[q * 4 + e] = f32_to_bf16_rne(vv[e] - bf16_bits_to_f32(h));
                    }
                }
            } else {
                const unsigned short* bsrc = (c < 2) ? aggb : (const unsigned short*)hsrc;
                int cc = (c < 2) ? c : c - 2;
                const uint4* s4 = (const uint4*)(bsrc + (size_t)rg * 128 + cc * 64 + half * 32);
#pragma unroll
                for (int q = 0; q < 4; q++) {
                    uint4 u = inb ? s4[q] : make_uint4(0, 0, 0, 0);
                    unsigned int uu[4] = {u.x, u.y, u.z, u.w};
#pragma unroll
                    for (int e = 0; e < 4; e++) {
                        hiA[q * 8 + e * 2 + 0] = (unsigned short)(uu[e] & 0xffffu);
                        hiA[q * 8 + e * 2 + 1] = (unsigned short)(uu[e] >> 16);
                    }
                }
            }
            unsigned int baseHi = ((mt_s * 2 + half) * 2 + 0) * 64;
#pragma unroll
            for (int g2 = 0; g2 < 4; g2++)
                Alds[baseHi + lidx + 16 * g2] = pack8(&hiA[g2 * 8]);
            if (haslo) {
#pragma unroll
                for (int g2 = 0; g2 < 4; g2++)
                    Alds[baseHi + 64 + lidx + 16 * g2] = pack8(&loA[g2 * 8]);
            }
        }
        __syncthreads();
#pragma unroll
        for (int kt = 0; kt < 2; kt++) {
            bf16x8 a0h = *(const bf16x8*)&Alds[(((w * 2 + 0) * 2 + kt) * 2 + 0) * 64 + lane];
            bf16x8 a1h = *(const bf16x8*)&Alds[(((w * 2 + 1) * 2 + kt) * 2 + 0) * 64 + lane];
            bf16x8 a0l, a1l;
            if (haslo) {
                a0l = *(const bf16x8*)&Alds[(((w * 2 + 0) * 2 + kt) * 2 + 1) * 64 + lane];
                a1l = *(const bf16x8*)&Alds[(((w * 2 + 1) * 2 + kt) * 2 + 1) * 64 + lane];
            }
#pragma unroll
            for (int nt = 0; nt < 8; nt++) {
                bf16x8 bhv = *(const bf16x8*)&Wlds[((kt * 8 + nt) * 2 + 0) * 64 + lane];
                bf16x8 blv = *(const bf16x8*)&Wlds[((kt * 8 + nt) * 2 + 1) * 64 + lane];
                acc[0][nt] = __builtin_amdgcn_mfma_f32_16x16x32_bf16(a0h, bhv, acc[0][nt], 0, 0, 0);
                acc[0][nt] = __builtin_amdgcn_mfma_f32_16x16x32_bf16(a0h, blv, acc[0][nt], 0, 0, 0);
                acc[1][nt] = __builtin_amdgcn_mfma_f32_16x16x32_bf16(a1h, bhv, acc[1][nt], 0, 0, 0);
                acc[1][nt] = __builtin_amdgcn_mfma_f32_16x16x32_bf16(a1h, blv, acc[1][nt], 0, 0, 0);
                if (haslo) {
                    acc[0][nt] = __builtin_amdgcn_mfma_f32_16x16x32_bf16(a0l, bhv, acc[0][nt], 0, 0, 0);
                    acc[1][nt] = __builtin_amdgcn_mfma_f32_16x16x32_bf16(a1l, bhv, acc[1][nt], 0, 0, 0);
                }
            }
        }
        __syncthreads();
    }

    const int col = lane & 15;
    const int g4 = lane >> 4;
    float bcol[8];
#pragma unroll
    for (int nt = 0; nt < 8; nt++) bcol[nt] = bias[nt * 16 + col];
    if (!FINAL) {
#pragma unroll
        for (int mt = 0; mt < 2; mt++) {
            int nodeBase = i0 + (w * 2 + mt) * 16 + g4 * 4;
#pragma unroll
            for (int reg = 0; reg < 4; reg++) {
                int node = nodeBase + reg;
                if (node < n) {
#pragma unroll
                    for (int nt = 0; nt < 8; nt++) {
                        float v = acc[mt][nt][reg] + bcol[nt];
                        v = v > 0.f ? v : 0.f;
                        hout[(size_t)node * 128 + nt * 16 + col] = f32_to_bf16_rne(v);
                    }
                }
            }
        }
    } else {
        float whc[8];
#pragma unroll
        for (int nt = 0; nt < 8; nt++) whc[nt] = Wh[nt * 16 + col];
        float bhv = bh[0];
#pragma unroll
        for (int mt = 0; mt < 2; mt++) {
            int nodeBase = i0 + (w * 2 + mt) * 16 + g4 * 4;
#pragma unroll
            for (int reg = 0; reg < 4; reg++) {
                float s = 0.f;
#pragma unroll
                for (int nt = 0; nt < 8; nt++) {
                    float v = acc[mt][nt][reg] + bcol[nt];
                    v = v > 0.f ? v : 0.f;
                    s += v * whc[nt];
                }
                s += __shfl_xor(s, 1);
                s += __shfl_xor(s, 2);
                s += __shfl_xor(s, 4);
                s += __shfl_xor(s, 8);
                int node = nodeBase + reg;
                if (col == 0 && node < n) logits[node] = s + bhv;
            }
        }
    }
}

extern "C" void kernel_launch(void* const* d_in, const int* in_sizes, int n_in,
                              void* d_out, int out_size, void* d_ws, size_t ws_size,
                              hipStream_t stream) {
    const float* x   = (const float*)d_in[0];
    const int*   ei  = (const int*)d_in[1];
    const float* Wn0 = (const float*)d_in[2];
    const float* Wr0 = (const float*)d_in[3];
    const float* b0  = (const float*)d_in[4];
    const float* Wn1 = (const float*)d_in[5];
    const float* Wr1 = (const float*)d_in[6];
    const float* b1  = (const float*)d_in[7];
    const float* Wh  = (const float*)d_in[8];
    const float* bh  = (const float*)d_in[9];
    float* logits = (float*)d_out;

    int N = in_sizes[0] / 128;
    int E = in_sizes[1] / 2;
    const int* src = ei;
    const int* dst = ei + E;

    int nbkt = (N + 31) >> 5;                       // 32-node coarse buckets
    int nTot = nbkt * 32;
    int HS = nbkt * NSB;                            // histogram entries
    int NB = (HS + 2047) / 2048;                    // scan1 blocks (hist)
    int NB2 = (nTot + 2047) / 2048;                 // scan1 blocks (nodecnt)
    int chunk = (((E + NSB - 1) / NSB) + 3) & ~3;   // multiple of 4 for int4 path

    char* ws = (char*)d_ws;
    size_t cur = 0;
    auto alloc = [&](size_t bytes) -> void* {
        void* p = ws + cur;
        cur += (bytes + 255) & ~(size_t)255;
        return p;
    };
    int* hist   = (int*)alloc((size_t)HS * 4);
    int* bsums  = (int*)alloc((size_t)NB * 4);
    int* bbase  = (int*)alloc((size_t)NB * 4);
    int* bsums2 = (int*)alloc((size_t)NB2 * 4);
    int* bbase2 = (int*)alloc((size_t)NB2 * 4);
    int* scrat  = (int*)alloc(256);
    int* nodecnt= (int*)alloc((size_t)nTot * 4);
    int* noff   = (int*)alloc((size_t)(nTot + 1) * 4);
    int* esrt   = (int*)alloc((size_t)E * 4);
    int* esrt2  = (int*)alloc((size_t)E * 4);
    unsigned short* xb  = (unsigned short*)alloc((size_t)N * 128 * 2);
    unsigned short* h0b = (unsigned short*)alloc((size_t)N * 128 * 2);
    unsigned short* agb = (unsigned short*)alloc((size_t)N * 128 * 2);
    uint4* Wsw0 = (uint4*)alloc(131072);
    uint4* Wsw1 = (uint4*)alloc(131072);
    (void)ws_size; (void)n_in; (void)out_size;

    // precision prep
    int n4 = N * 32;
    hipLaunchKernelGGL(cvt_bf16_kernel, dim3((n4 + 255) / 256), dim3(256), 0, stream,
                       (const float4*)x, (ushort4*)xb, n4);
    hipLaunchKernelGGL(swizzle_w_kernel, dim3(16), dim3(256), 0, stream, Wn0, Wr0, Wsw0);
    hipLaunchKernelGGL(swizzle_w_kernel, dim3(16), dim3(256), 0, stream, Wn1, Wr1, Wsw1);

    // counting sort: bucket histogram + per-node histogram, scans, scatter, node sort
    hipLaunchKernelGGL(zero_kernel,   dim3((nTot + 255) / 256), dim3(256), 0, stream, nodecnt, nTot);
    hipLaunchKernelGGL(hist32,        dim3(NSB), dim3(256), 0, stream, dst, hist, nodecnt, E, nbkt, chunk);
    hipLaunchKernelGGL(scan1_kernel,  dim3(NB),  dim3(256), 0, stream, hist, hist, bsums, HS);
    hipLaunchKernelGGL(scan2_kernel,  dim3(1),   dim3(64),  0, stream, bsums, bbase, NB, scrat);
    hipLaunchKernelGGL(scan3b_kernel, dim3((HS + 255) / 256), dim3(256), 0, stream, hist, bbase, HS);
    hipLaunchKernelGGL(scan1_kernel,  dim3(NB2), dim3(256), 0, stream, nodecnt, noff, bsums2, nTot);
    hipLaunchKernelGGL(scan2_kernel,  dim3(1),   dim3(64),  0, stream, bsums2, bbase2, NB2, &noff[nTot]);
    hipLaunchKernelGGL(scan3b_kernel, dim3((nTot + 255) / 256), dim3(256), 0, stream, noff, bbase2, nTot);
    hipLaunchKernelGGL(scatter32,     dim3(NSB), dim3(256), 0, stream, src, dst, hist, esrt, E, nbkt, chunk);
    hipLaunchKernelGGL(sort2f,        dim3(nbkt), dim3(256), 0, stream, esrt, hist, noff, esrt2, E, nbkt);

    int gUpd = (N + 127) / 128;

    // Layer 0
    hipLaunchKernelGGL(agg_gather, dim3(nbkt), dim3(256), 0, stream, xb, esrt2, noff, agb, N);
    hipLaunchKernelGGL((update_mfma<0, false>), dim3(gUpd), dim3(256), 0, stream,
                       agb, (const void*)x, Wsw0, b0, h0b, nullptr, nullptr, nullptr, N);
    // Layer 1 + fused head
    hipLaunchKernelGGL(agg_gather, dim3(nbkt), dim3(256), 0, stream, h0b, esrt2, noff, agb, N);
    hipLaunchKernelGGL((update_mfma<1, true>), dim3(gUpd), dim3(256), 0, stream,
                       agb, (const void*)h0b, Wsw1, b1, nullptr, Wh, bh, logits, N);
}

// Round 4
// 362.207 us; speedup vs baseline: 1.3049x; 1.3049x over previous
//
#include <hip/hip_runtime.h>

#define THREADS 256
#define SCAN_ITEMS 8    // 2048 elements per scan block
#define NSB 256         // sort blocks: full-chip grid; run length E/NSB = 6250
#define BKT_MAX 3200    // >= ceil(N/32)
#define CHUNK 1024      // agg staging chunk (edges); bucket mean 512, sigma ~23

typedef float f32x4 __attribute__((ext_vector_type(4)));
typedef __bf16 bf16x8 __attribute__((ext_vector_type(8)));
typedef int intx4 __attribute__((ext_vector_type(4)));

__device__ inline unsigned short f32_to_bf16_rne(float f) {
    unsigned int u = __float_as_uint(f);
    unsigned int r = u + 0x7fffu + ((u >> 16) & 1u);
    return (unsigned short)(r >> 16);
}
__device__ inline float bf16_bits_to_f32(unsigned short h) {
    return __uint_as_float(((unsigned int)h) << 16);
}
__device__ inline uint4 pack8(const unsigned short* s) {
    uint4 u;
    u.x = (unsigned int)s[0] | ((unsigned int)s[1] << 16);
    u.y = (unsigned int)s[2] | ((unsigned int)s[3] << 16);
    u.z = (unsigned int)s[4] | ((unsigned int)s[5] << 16);
    u.w = (unsigned int)s[6] | ((unsigned int)s[7] << 16);
    return u;
}

// ---------------- coarse counting sort (32-node buckets) ----------------
__global__ __launch_bounds__(256) void hist32(const int* __restrict__ dst,
                                              int* __restrict__ hist,
                                              int E, int nbkt, int chunk) {
    __shared__ int lh[BKT_MAX];
    const int tid = threadIdx.x, blk = blockIdx.x;
    for (int i = tid; i < nbkt; i += 256) lh[i] = 0;
    __syncthreads();
    int s = blk * chunk, e = s + chunk; if (e > E) e = E;
    if (((size_t)dst & 15) == 0) {
        int n4 = (e > s) ? ((e - s) >> 2) : 0;
        const intx4* d4p = (const intx4*)(dst + s);
        for (int i = tid; i < n4; i += 256) {
            intx4 d4 = d4p[i];
#pragma unroll
            for (int k = 0; k < 4; k++) atomicAdd(&lh[d4[k] >> 5], 1);
        }
        for (int j = s + (n4 << 2) + tid; j < e; j += 256) atomicAdd(&lh[dst[j] >> 5], 1);
    } else {
        for (int j = s + tid; j < e; j += 256) atomicAdd(&lh[dst[j] >> 5], 1);
    }
    __syncthreads();
    for (int i = tid; i < nbkt; i += 256) hist[i * NSB + blk] = lh[i];
}

__global__ void scan1_kernel(const int* __restrict__ cnt, int* __restrict__ off,
                             int* __restrict__ bsums, int n) {
    __shared__ int sdata[THREADS];
    int base = blockIdx.x * (THREADS * SCAN_ITEMS) + threadIdx.x * SCAN_ITEMS;
    int vals[SCAN_ITEMS];
    int tsum = 0;
#pragma unroll
    for (int k = 0; k < SCAN_ITEMS; k++) {
        int idx = base + k;
        int v = (idx < n) ? cnt[idx] : 0;
        vals[k] = tsum;
        tsum += v;
    }
    sdata[threadIdx.x] = tsum;
    __syncthreads();
    for (int s = 1; s < THREADS; s <<= 1) {
        int y = (threadIdx.x >= (unsigned)s) ? sdata[threadIdx.x - s] : 0;
        __syncthreads();
        sdata[threadIdx.x] += y;
        __syncthreads();
    }
    int texcl = sdata[threadIdx.x] - tsum;
#pragma unroll
    for (int k = 0; k < SCAN_ITEMS; k++) {
        int idx = base + k;
        if (idx < n) off[idx] = texcl + vals[k];
    }
    if (threadIdx.x == THREADS - 1) bsums[blockIdx.x] = sdata[THREADS - 1];
}

// Wave-parallel block-sum scan (replaces the old single-thread serial scan,
// which paid ~nb dependent L2 round-trips).
__global__ void scan2_wave(const int* __restrict__ bsums, int* __restrict__ bbase,
                           int nb, int* __restrict__ offN) {
    const int lane = threadIdx.x;   // 64 threads, 1 block
    int carry = 0;
    for (int base = 0; base < nb; base += 64) {
        int i = base + lane;
        int v = (i < nb) ? bsums[i] : 0;
        int x = v;
#pragma unroll
        for (int s = 1; s < 64; s <<= 1) {
            int y = __shfl_up(x, s);
            if (lane >= s) x += y;
        }
        if (i < nb) bbase[i] = carry + x - v;
        carry += __shfl(x, 63);
    }
    if (lane == 0) *offN = carry;
}

__global__ void scan3b_kernel(int* __restrict__ off, const int* __restrict__ bbase, int n) {
    int i = blockIdx.x * blockDim.x + threadIdx.x;
    if (i < n) off[i] += bbase[i >> 11];
}

// Pass 2: stable scatter into bucket-grouped array. Payload: src | dst_local<<17.
__global__ __launch_bounds__(256) void scatter32(const int* __restrict__ src,
                                                 const int* __restrict__ dst,
                                                 const int* __restrict__ hstS,
                                                 int* __restrict__ esrt,
                                                 int E, int nbkt, int chunk) {
    __shared__ int cur[BKT_MAX];
    const int tid = threadIdx.x, blk = blockIdx.x;
    for (int i = tid; i < nbkt; i += 256) cur[i] = hstS[i * NSB + blk];
    __syncthreads();
    int s = blk * chunk, e = s + chunk; if (e > E) e = E;
    if ((((size_t)dst | (size_t)src) & 15) == 0) {
        int n4 = (e > s) ? ((e - s) >> 2) : 0;
        const intx4* d4p = (const intx4*)(dst + s);
        const intx4* s4p = (const intx4*)(src + s);
        for (int i = tid; i < n4; i += 256) {
            intx4 d4 = d4p[i];
            intx4 s4 = s4p[i];
#pragma unroll
            for (int k = 0; k < 4; k++) {
                int d = d4[k];
                int p = atomicAdd(&cur[d >> 5], 1);
                esrt[p] = s4[k] | ((d & 31) << 17);
            }
        }
        for (int j = s + (n4 << 2) + tid; j < e; j += 256) {
            int d = dst[j];
            int p = atomicAdd(&cur[d >> 5], 1);
            esrt[p] = src[j] | ((d & 31) << 17);
        }
    } else {
        for (int j = s + tid; j < e; j += 256) {
            int d = dst[j];
            int p = atomicAdd(&cur[d >> 5], 1);
            esrt[p] = src[j] | ((d & 31) << 17);
        }
    }
}

// ---------------- precision prep ----------------
__global__ void cvt_bf16_kernel(const float4* __restrict__ x, ushort4* __restrict__ o, int n4) {
    int i = blockIdx.x * blockDim.x + threadIdx.x;
    if (i < n4) {
        float4 v = x[i];
        ushort4 r;
        r.x = f32_to_bf16_rne(v.x);
        r.y = f32_to_bf16_rne(v.y);
        r.z = f32_to_bf16_rne(v.z);
        r.w = f32_to_bf16_rne(v.w);
        o[i] = r;
    }
}

// Swizzled hi/lo bf16 weights. W256[k][n]: k<128 -> Wn, else Wr.
__global__ void swizzle_w_kernel(const float* __restrict__ Wn, const float* __restrict__ Wr,
                                 uint4* __restrict__ out) {
    int id = blockIdx.x * blockDim.x + threadIdx.x;
    if (id >= 4096) return;
    int lane = id & 63;
    int nt = (id >> 6) & 7;
    int t = id >> 9;
    int kbase = t * 32 + (lane >> 4) * 8;
    int col = nt * 16 + (lane & 15);
    unsigned short hi[8], lo[8];
#pragma unroll
    for (int j = 0; j < 8; j++) {
        int k = kbase + j;
        const float* W = (k < 128) ? (Wn + (size_t)k * 128) : (Wr + (size_t)(k - 128) * 128);
        float v = W[col];
        unsigned short h = f32_to_bf16_rne(v);
        hi[j] = h;
        lo[j] = f32_to_bf16_rne(v - bf16_bits_to_f32(h));
    }
    out[(size_t)((t * 8 + nt) * 2 + 0) * 64 + lane] = pack8(hi);
    out[(size_t)((t * 8 + nt) * 2 + 1) * 64 + lane] = pack8(lo);
}

// ---------------- bucketed aggregation: LDS sort + ping-pong gather ----------
// Fast path: LDS counting-sort of the bucket's <=1024 edges, then each wave
// walks its 8 nodes' contiguous edge range with a 2-deep ping-pong of 8-edge
// batches (8-16 row loads in flight; keys from LDS, node offsets preloaded
// to registers so the flush path touches no memory). Fallback: multi-chunk.
__global__ __launch_bounds__(256) void agg_bucket(const unsigned short* __restrict__ hb,
                                                  const int* __restrict__ hstS,
                                                  const int* __restrict__ esrt,
                                                  unsigned short* __restrict__ aggb,
                                                  int E, int nbkt, int n) {
    __shared__ int stage[CHUNK];
    __shared__ int sorted[CHUNK];
    __shared__ int cnt[32];
    __shared__ int coff[33];
    const int tid = threadIdx.x, lane = tid & 63, w = tid >> 6;
    const int b = blockIdx.x;

    const int p0 = hstS[b * NSB];
    const int p1 = (b + 1 < nbkt) ? hstS[(b + 1) * NSB] : E;

    if (p1 - p0 <= CHUNK) {
        // ---- sort chunk into LDS ----
        int m = p1 - p0;
        for (int i = tid; i < m; i += 256) stage[i] = esrt[p0 + i];
        if (tid < 32) cnt[tid] = 0;
        __syncthreads();
        for (int i = tid; i < m; i += 256) atomicAdd(&cnt[(stage[i] >> 17) & 31], 1);
        __syncthreads();
        if (tid < 32) {
            int v = cnt[tid];
            int x = v;
#pragma unroll
            for (int s = 1; s < 32; s <<= 1) {
                int y = __shfl_up(x, s);
                if (lane >= s) x += y;
            }
            coff[tid + 1] = x;
            if (tid == 0) coff[0] = 0;
            cnt[tid] = x - v;
        }
        __syncthreads();
        for (int i = tid; i < m; i += 256) {
            int pk = stage[i];
            int p = atomicAdd(&cnt[(pk >> 17) & 31], 1);
            sorted[p] = pk;
        }
        __syncthreads();

        // ---- per-wave node offsets into registers (no LDS in flush path) ----
        int no[9];
#pragma unroll
        for (int i = 0; i <= 8; i++) no[i] = coff[w * 8 + i];
        const int s = no[0], e2 = no[8];
        int curL = 0;               // local node in [0,8]
        float ax = 0.f, ay = 0.f;

        auto flushTo = [&](int tgt) {
            while (curL < tgt) {
                int node = b * 32 + w * 8 + curL;
                int d = no[curL + 1] - no[curL];
                float inv = 1.0f / (float)(d > 1 ? d : 1);
                unsigned int o = (unsigned int)f32_to_bf16_rne(ax * inv)
                               | ((unsigned int)f32_to_bf16_rne(ay * inv) << 16);
                if (node < n)
                    *(unsigned int*)(aggb + (size_t)node * 128 + lane * 2) = o;
                ax = 0.f; ay = 0.f; ++curL;
            }
        };
        auto issue = [&](unsigned int* v, int* nd, int base) {
#pragma unroll
            for (int j = 0; j < 8; j++) {
                int pk = sorted[base + j];              // broadcast LDS read
                nd[j] = ((pk >> 17) & 31) - w * 8;      // local node target
                v[j] = *(const unsigned int*)(hb + (size_t)(pk & 0x1FFFF) * 128 + lane * 2);
            }
        };
        auto consume = [&](const unsigned int* v, const int* nd) {
#pragma unroll
            for (int j = 0; j < 8; j++) {
                flushTo(nd[j]);
                ax += __uint_as_float(v[j] << 16);
                ay += __uint_as_float(v[j] & 0xffff0000u);
            }
        };

        const int nb8 = (e2 - s) >> 3;
        unsigned int vA[8], vB[8];
        int ndA[8], ndB[8];
        if (nb8 > 0) {
            issue(vA, ndA, s);
            int k = 1;
            for (; k + 1 < nb8; k += 2) {
                issue(vB, ndB, s + k * 8);
                consume(vA, ndA);
                issue(vA, ndA, s + k * 8 + 8);
                consume(vB, ndB);
            }
            if (k < nb8) {
                issue(vB, ndB, s + k * 8);
                consume(vA, ndA);
                consume(vB, ndB);
            } else {
                consume(vA, ndA);
            }
        }
        for (int i = s + (nb8 << 3); i < e2; i++) {
            int pk = sorted[i];
            flushTo(((pk >> 17) & 31) - w * 8);
            unsigned int vv = *(const unsigned int*)(hb + (size_t)(pk & 0x1FFFF) * 128 + lane * 2);
            ax += __uint_as_float(vv << 16);
            ay += __uint_as_float(vv & 0xffff0000u);
        }
        flushTo(8);
        return;
    }

    // ---- fallback: multi-chunk bucket ----
    float accx[8], accy[8];
    int dcnt[8];
#pragma unroll
    for (int nl = 0; nl < 8; nl++) { accx[nl] = 0.f; accy[nl] = 0.f; dcnt[nl] = 0; }
    for (int base = p0; base < p1; base += CHUNK) {
        int m = p1 - base; if (m > CHUNK) m = CHUNK;
        for (int i = tid; i < m; i += 256) stage[i] = esrt[base + i];
        if (tid < 32) cnt[tid] = 0;
        __syncthreads();
        for (int i = tid; i < m; i += 256) atomicAdd(&cnt[(stage[i] >> 17) & 31], 1);
        __syncthreads();
        if (tid < 32) {
            int v = cnt[tid];
            int x = v;
#pragma unroll
            for (int s = 1; s < 32; s <<= 1) {
                int y = __shfl_up(x, s);
                if (lane >= s) x += y;
            }
            coff[tid + 1] = x;
            if (tid == 0) coff[0] = 0;
            cnt[tid] = x - v;
        }
        __syncthreads();
        for (int i = tid; i < m; i += 256) {
            int pk = stage[i];
            int p = atomicAdd(&cnt[(pk >> 17) & 31], 1);
            sorted[p] = pk;
        }
        __syncthreads();
#pragma unroll
        for (int nl = 0; nl < 8; nl++) {
            int node_l = w * 8 + nl;
            int s = coff[node_l], e2 = coff[node_l + 1];
            dcnt[nl] += e2 - s;
            float ax = accx[nl], ay = accy[nl];
            int i = s;
            for (; i + 8 <= e2; i += 8) {
                unsigned int v[8];
#pragma unroll
                for (int j = 0; j < 8; j++) {
                    int sj = sorted[i + j] & 0x1FFFF;
                    v[j] = *(const unsigned int*)(hb + (size_t)sj * 128 + lane * 2);
                }
#pragma unroll
                for (int j = 0; j < 8; j++) {
                    ax += __uint_as_float(v[j] << 16);
                    ay += __uint_as_float(v[j] & 0xffff0000u);
                }
            }
            for (; i < e2; i++) {
                int sj = sorted[i] & 0x1FFFF;
                unsigned int vv = *(const unsigned int*)(hb + (size_t)sj * 128 + lane * 2);
                ax += __uint_as_float(vv << 16);
                ay += __uint_as_float(vv & 0xffff0000u);
            }
            accx[nl] = ax; accy[nl] = ay;
        }
        __syncthreads();
    }
#pragma unroll
    for (int nl = 0; nl < 8; nl++) {
        int node = b * 32 + w * 8 + nl;
        if (node < n) {
            int d = dcnt[nl];
            float inv = 1.0f / (float)(d > 1 ? d : 1);
            unsigned int o = (unsigned int)f32_to_bf16_rne(accx[nl] * inv)
                           | ((unsigned int)f32_to_bf16_rne(accy[nl] * inv) << 16);
            *(unsigned int*)(aggb + (size_t)node * 128 + lane * 2) = o;
        }
    }
}

// ---------------- fused SAGE update via split-bf16 MFMA ----------------
template <int LAYER, bool FINAL>
__global__ __launch_bounds__(256, 2) void update_mfma(
    const unsigned short* __restrict__ aggb, const void* __restrict__ hsrc,
    const uint4* __restrict__ Wsw, const float* __restrict__ bias,
    unsigned short* __restrict__ hout,
    const float* __restrict__ Wh, const float* __restrict__ bh,
    float* __restrict__ logits, int n) {
    __shared__ uint4 Alds[2048];
    __shared__ uint4 Wlds[2048];
    const int tid = threadIdx.x;
    const int lane = tid & 63;
    const int w = tid >> 6;
    const int i0 = blockIdx.x * 128;

    f32x4 acc[2][8];
#pragma unroll
    for (int mt = 0; mt < 2; mt++)
#pragma unroll
        for (int nt = 0; nt < 8; nt++) acc[mt][nt] = (f32x4)0.f;

    const int r = tid >> 1;
    const int half = tid & 1;
    const int rg = i0 + r;
    const bool inb = rg < n;
    const int mt_s = r >> 4;
    const int lidx = r & 15;

    for (int c = 0; c < 4; c++) {
        const bool haslo = (LAYER == 0 && c >= 2);
        {
            const uint4* srcW = Wsw + (size_t)c * 2048;
#pragma unroll
            for (int g = 0; g < 8; g++) Wlds[g * 256 + tid] = srcW[g * 256 + tid];
        }
        {
            unsigned short hiA[32], loA[32];
            if (LAYER == 0 && c >= 2) {
                const float4* s4 = (const float4*)((const float*)hsrc + (size_t)rg * 128 +
                                                   (c - 2) * 64 + half * 32);
#pragma unroll
                for (int q = 0; q < 8; q++) {
                    float4 f = inb ? s4[q] : make_float4(0.f, 0.f, 0.f, 0.f);
                    float vv[4] = {f.x, f.y, f.z, f.w};
#pragma unroll
                    for (int e = 0; e < 4; e++) {
                        unsigned short h = f32_to_bf16_rne(vv[e]);
                        hiA[q * 4 + e] = h;
                        loA[q * 4 + e] = f32_to_bf16_rne(vv[e] - bf16_bits_to_f32(h));
                    }
                }
            } else {
                const unsigned short* bsrc = (c < 2) ? aggb : (const unsigned short*)hsrc;
                int cc = (c < 2) ? c : c - 2;
                const uint4* s4 = (const uint4*)(bsrc + (size_t)rg * 128 + cc * 64 + half * 32);
#pragma unroll
                for (int q = 0; q < 4; q++) {
                    uint4 u = inb ? s4[q] : make_uint4(0, 0, 0, 0);
                    unsigned int uu[4] = {u.x, u.y, u.z, u.w};
#pragma unroll
                    for (int e = 0; e < 4; e++) {
                        hiA[q * 8 + e * 2 + 0] = (unsigned short)(uu[e] & 0xffffu);
                        hiA[q * 8 + e * 2 + 1] = (unsigned short)(uu[e] >> 16);
                    }
                }
            }
            unsigned int baseHi = ((mt_s * 2 + half) * 2 + 0) * 64;
#pragma unroll
            for (int g2 = 0; g2 < 4; g2++)
                Alds[baseHi + lidx + 16 * g2] = pack8(&hiA[g2 * 8]);
            if (haslo) {
#pragma unroll
                for (int g2 = 0; g2 < 4; g2++)
                    Alds[baseHi + 64 + lidx + 16 * g2] = pack8(&loA[g2 * 8]);
            }
        }
        __syncthreads();
#pragma unroll
        for (int kt = 0; kt < 2; kt++) {
            bf16x8 a0h = *(const bf16x8*)&Alds[(((w * 2 + 0) * 2 + kt) * 2 + 0) * 64 + lane];
            bf16x8 a1h = *(const bf16x8*)&Alds[(((w * 2 + 1) * 2 + kt) * 2 + 0) * 64 + lane];
            bf16x8 a0l, a1l;
            if (haslo) {
                a0l = *(const bf16x8*)&Alds[(((w * 2 + 0) * 2 + kt) * 2 + 1) * 64 + lane];
                a1l = *(const bf16x8*)&Alds[(((w * 2 + 1) * 2 + kt) * 2 + 1) * 64 + lane];
            }
#pragma unroll
            for (int nt = 0; nt < 8; nt++) {
                bf16x8 bhv = *(const bf16x8*)&Wlds[((kt * 8 + nt) * 2 + 0) * 64 + lane];
                bf16x8 blv = *(const bf16x8*)&Wlds[((kt * 8 + nt) * 2 + 1) * 64 + lane];
                acc[0][nt] = __builtin_amdgcn_mfma_f32_16x16x32_bf16(a0h, bhv, acc[0][nt], 0, 0, 0);
                acc[0][nt] = __builtin_amdgcn_mfma_f32_16x16x32_bf16(a0h, blv, acc[0][nt], 0, 0, 0);
                acc[1][nt] = __builtin_amdgcn_mfma_f32_16x16x32_bf16(a1h, bhv, acc[1][nt], 0, 0, 0);
                acc[1][nt] = __builtin_amdgcn_mfma_f32_16x16x32_bf16(a1h, blv, acc[1][nt], 0, 0, 0);
                if (haslo) {
                    acc[0][nt] = __builtin_amdgcn_mfma_f32_16x16x32_bf16(a0l, bhv, acc[0][nt], 0, 0, 0);
                    acc[1][nt] = __builtin_amdgcn_mfma_f32_16x16x32_bf16(a1l, bhv, acc[1][nt], 0, 0, 0);
                }
            }
        }
        __syncthreads();
    }

    const int col = lane & 15;
    const int g4 = lane >> 4;
    float bcol[8];
#pragma unroll
    for (int nt = 0; nt < 8; nt++) bcol[nt] = bias[nt * 16 + col];
    if (!FINAL) {
#pragma unroll
        for (int mt = 0; mt < 2; mt++) {
            int nodeBase = i0 + (w * 2 + mt) * 16 + g4 * 4;
#pragma unroll
            for (int reg = 0; reg < 4; reg++) {
                int node = nodeBase + reg;
                if (node < n) {
#pragma unroll
                    for (int nt = 0; nt < 8; nt++) {
                        float v = acc[mt][nt][reg] + bcol[nt];
                        v = v > 0.f ? v : 0.f;
                        hout[(size_t)node * 128 + nt * 16 + col] = f32_to_bf16_rne(v);
                    }
                }
            }
        }
    } else {
        float whc[8];
#pragma unroll
        for (int nt = 0; nt < 8; nt++) whc[nt] = Wh[nt * 16 + col];
        float bhv = bh[0];
#pragma unroll
        for (int mt = 0; mt < 2; mt++) {
            int nodeBase = i0 + (w * 2 + mt) * 16 + g4 * 4;
#pragma unroll
            for (int reg = 0; reg < 4; reg++) {
                float s = 0.f;
#pragma unroll
                for (int nt = 0; nt < 8; nt++) {
                    float v = acc[mt][nt][reg] + bcol[nt];
                    v = v > 0.f ? v : 0.f;
                    s += v * whc[nt];
                }
                s += __shfl_xor(s, 1);
                s += __shfl_xor(s, 2);
                s += __shfl_xor(s, 4);
                s += __shfl_xor(s, 8);
                int node = nodeBase + reg;
                if (col == 0 && node < n) logits[node] = s + bhv;
            }
        }
    }
}

extern "C" void kernel_launch(void* const* d_in, const int* in_sizes, int n_in,
                              void* d_out, int out_size, void* d_ws, size_t ws_size,
                              hipStream_t stream) {
    const float* x   = (const float*)d_in[0];
    const int*   ei  = (const int*)d_in[1];
    const float* Wn0 = (const float*)d_in[2];
    const float* Wr0 = (const float*)d_in[3];
    const float* b0  = (const float*)d_in[4];
    const float* Wn1 = (const float*)d_in[5];
    const float* Wr1 = (const float*)d_in[6];
    const float* b1  = (const float*)d_in[7];
    const float* Wh  = (const float*)d_in[8];
    const float* bh  = (const float*)d_in[9];
    float* logits = (float*)d_out;

    int N = in_sizes[0] / 128;
    int E = in_sizes[1] / 2;
    const int* src = ei;
    const int* dst = ei + E;

    int nbkt = (N + 31) >> 5;                       // 32-node coarse buckets
    int HS = nbkt * NSB;                            // histogram entries
    int NB = (HS + 2047) / 2048;                    // scan1 blocks
    int chunk = (((E + NSB - 1) / NSB) + 3) & ~3;   // multiple of 4 for int4 path

    char* ws = (char*)d_ws;
    size_t cur = 0;
    auto alloc = [&](size_t bytes) -> void* {
        void* p = ws + cur;
        cur += (bytes + 255) & ~(size_t)255;
        return p;
    };
    int* hist  = (int*)alloc((size_t)HS * 4);
    int* bsums = (int*)alloc((size_t)NB * 4);
    int* bbase = (int*)alloc((size_t)NB * 4);
    int* scrat = (int*)alloc(256);
    int* esrt  = (int*)alloc((size_t)E * 4);
    unsigned short* xb  = (unsigned short*)alloc((size_t)N * 128 * 2);
    unsigned short* h0b = (unsigned short*)alloc((size_t)N * 128 * 2);
    unsigned short* agb = (unsigned short*)alloc((size_t)N * 128 * 2);
    uint4* Wsw0 = (uint4*)alloc(131072);
    uint4* Wsw1 = (uint4*)alloc(131072);
    (void)ws_size; (void)n_in; (void)out_size;

    // precision prep
    int n4 = N * 32;
    hipLaunchKernelGGL(cvt_bf16_kernel, dim3((n4 + 255) / 256), dim3(256), 0, stream,
                       (const float4*)x, (ushort4*)xb, n4);
    hipLaunchKernelGGL(swizzle_w_kernel, dim3(16), dim3(256), 0, stream, Wn0, Wr0, Wsw0);
    hipLaunchKernelGGL(swizzle_w_kernel, dim3(16), dim3(256), 0, stream, Wn1, Wr1, Wsw1);

    // coarse counting sort (NSB=256 full-chip grids, int4 edge reads)
    hipLaunchKernelGGL(hist32,        dim3(NSB), dim3(256), 0, stream, dst, hist, E, nbkt, chunk);
    hipLaunchKernelGGL(scan1_kernel,  dim3(NB),  dim3(256), 0, stream, hist, hist, bsums, HS);
    hipLaunchKernelGGL(scan2_wave,    dim3(1),   dim3(64),  0, stream, bsums, bbase, NB, scrat);
    hipLaunchKernelGGL(scan3b_kernel, dim3((HS + 255) / 256), dim3(256), 0, stream, hist, bbase, HS);
    hipLaunchKernelGGL(scatter32,     dim3(NSB), dim3(256), 0, stream, src, dst, hist, esrt, E, nbkt, chunk);

    int gUpd = (N + 127) / 128;

    // Layer 0
    hipLaunchKernelGGL(agg_bucket, dim3(nbkt), dim3(256), 0, stream, xb, hist, esrt, agb, E, nbkt, N);
    hipLaunchKernelGGL((update_mfma<0, false>), dim3(gUpd), dim3(256), 0, stream,
                       agb, (const void*)x, Wsw0, b0, h0b, nullptr, nullptr, nullptr, N);
    // Layer 1 + fused head
    hipLaunchKernelGGL(agg_bucket, dim3(nbkt), dim3(256), 0, stream, h0b, hist, esrt, agb, E, nbkt, N);
    hipLaunchKernelGGL((update_mfma<1, true>), dim3(gUpd), dim3(256), 0, stream,
                       agb, (const void*)h0b, Wsw1, b1, nullptr, Wh, bh, logits, N);
}

// Round 5
// 345.713 us; speedup vs baseline: 1.3672x; 1.0477x over previous
//
#include <hip/hip_runtime.h>

#define THREADS 256
#define SCAN_ITEMS 8    // 2048 elements per scan block
#define NSB 128         // sort blocks: run length E/NSB = 12500 edges
#define BKT_MAX 3200    // >= ceil(N/32)
#define CHUNK 1024      // agg staging chunk (edges); bucket mean 512, sigma ~23

typedef float f32x4 __attribute__((ext_vector_type(4)));
typedef float floatx2 __attribute__((ext_vector_type(2)));
typedef __bf16 bf16x8 __attribute__((ext_vector_type(8)));
typedef int intx4 __attribute__((ext_vector_type(4)));

__device__ inline unsigned short f32_to_bf16_rne(float f) {
    unsigned int u = __float_as_uint(f);
    unsigned int r = u + 0x7fffu + ((u >> 16) & 1u);
    return (unsigned short)(r >> 16);
}
__device__ inline float bf16_bits_to_f32(unsigned short h) {
    return __uint_as_float(((unsigned int)h) << 16);
}
__device__ inline uint4 pack8(const unsigned short* s) {
    uint4 u;
    u.x = (unsigned int)s[0] | ((unsigned int)s[1] << 16);
    u.y = (unsigned int)s[2] | ((unsigned int)s[3] << 16);
    u.z = (unsigned int)s[4] | ((unsigned int)s[5] << 16);
    u.w = (unsigned int)s[6] | ((unsigned int)s[7] << 16);
    return u;
}

// ---------------- fused prep: hist (blocks 0..NSB-1) + weight swizzle
// (NSB..NSB+31) + x->bf16 cvt (rest). One launch instead of three. ----------
__global__ __launch_bounds__(256) void prep(
    const int* __restrict__ dst, int* __restrict__ hist, int E, int nbkt, int chunk,
    const float4* __restrict__ x4, ushort4* __restrict__ xb4, int n4,
    const float* __restrict__ Wn0, const float* __restrict__ Wr0, uint4* __restrict__ Wsw0,
    const float* __restrict__ Wn1, const float* __restrict__ Wr1, uint4* __restrict__ Wsw1) {
    __shared__ int lh[BKT_MAX];
    const int tid = threadIdx.x, blk = blockIdx.x;
    if (blk < NSB) {
        for (int i = tid; i < nbkt; i += 256) lh[i] = 0;
        __syncthreads();
        int s = blk * chunk, e = s + chunk; if (e > E) e = E;
        int n4e = (e > s) ? ((e - s) >> 2) : 0;
        const intx4* d4p = (const intx4*)(dst + s);
        for (int i = tid; i < n4e; i += 256) {
            intx4 d4 = d4p[i];
#pragma unroll
            for (int k = 0; k < 4; k++) atomicAdd(&lh[d4[k] >> 5], 1);
        }
        for (int j = s + (n4e << 2) + tid; j < e; j += 256) atomicAdd(&lh[dst[j] >> 5], 1);
        __syncthreads();
        for (int i = tid; i < nbkt; i += 256) hist[i * NSB + blk] = lh[i];
    } else if (blk < NSB + 32) {
        int b2 = blk - NSB;
        const float* Wn = (b2 < 16) ? Wn0 : Wn1;
        const float* Wr = (b2 < 16) ? Wr0 : Wr1;
        uint4* out = (b2 < 16) ? Wsw0 : Wsw1;
        int id = (b2 & 15) * 256 + tid;
        int lane = id & 63;
        int nt = (id >> 6) & 7;
        int t = id >> 9;
        int kbase = t * 32 + (lane >> 4) * 8;
        int col = nt * 16 + (lane & 15);
        unsigned short hi[8], lo[8];
#pragma unroll
        for (int j = 0; j < 8; j++) {
            int k = kbase + j;
            const float* W = (k < 128) ? (Wn + (size_t)k * 128) : (Wr + (size_t)(k - 128) * 128);
            float v = W[col];
            unsigned short h = f32_to_bf16_rne(v);
            hi[j] = h;
            lo[j] = f32_to_bf16_rne(v - bf16_bits_to_f32(h));
        }
        out[(size_t)((t * 8 + nt) * 2 + 0) * 64 + lane] = pack8(hi);
        out[(size_t)((t * 8 + nt) * 2 + 1) * 64 + lane] = pack8(lo);
    } else {
        int i = (blk - NSB - 32) * 256 + tid;
        if (i < n4) {
            float4 v = x4[i];
            ushort4 r;
            r.x = f32_to_bf16_rne(v.x);
            r.y = f32_to_bf16_rne(v.y);
            r.z = f32_to_bf16_rne(v.z);
            r.w = f32_to_bf16_rne(v.w);
            xb4[i] = r;
        }
    }
}

__global__ void scan1_kernel(const int* __restrict__ cnt, int* __restrict__ off,
                             int* __restrict__ bsums, int n) {
    __shared__ int sdata[THREADS];
    int base = blockIdx.x * (THREADS * SCAN_ITEMS) + threadIdx.x * SCAN_ITEMS;
    int vals[SCAN_ITEMS];
    int tsum = 0;
#pragma unroll
    for (int k = 0; k < SCAN_ITEMS; k++) {
        int idx = base + k;
        int v = (idx < n) ? cnt[idx] : 0;
        vals[k] = tsum;
        tsum += v;
    }
    sdata[threadIdx.x] = tsum;
    __syncthreads();
    for (int s = 1; s < THREADS; s <<= 1) {
        int y = (threadIdx.x >= (unsigned)s) ? sdata[threadIdx.x - s] : 0;
        __syncthreads();
        sdata[threadIdx.x] += y;
        __syncthreads();
    }
    int texcl = sdata[threadIdx.x] - tsum;
#pragma unroll
    for (int k = 0; k < SCAN_ITEMS; k++) {
        int idx = base + k;
        if (idx < n) off[idx] = texcl + vals[k];
    }
    if (threadIdx.x == THREADS - 1) bsums[blockIdx.x] = sdata[THREADS - 1];
}

// Wave-parallel block-sum scan.
__global__ void scan2_wave(const int* __restrict__ bsums, int* __restrict__ bbase,
                           int nb, int* __restrict__ offN) {
    const int lane = threadIdx.x;   // 64 threads, 1 block
    int carry = 0;
    for (int base = 0; base < nb; base += 64) {
        int i = base + lane;
        int v = (i < nb) ? bsums[i] : 0;
        int x = v;
#pragma unroll
        for (int s = 1; s < 64; s <<= 1) {
            int y = __shfl_up(x, s);
            if (lane >= s) x += y;
        }
        if (i < nb) bbase[i] = carry + x - v;
        carry += __shfl(x, 63);
    }
    if (lane == 0) *offN = carry;
}

__global__ void scan3b_kernel(int* __restrict__ off, const int* __restrict__ bbase, int n) {
    int i = blockIdx.x * blockDim.x + threadIdx.x;
    if (i < n) off[i] += bbase[i >> 11];
}

// Pass 2: stable scatter into bucket-grouped array.
// Payload: (src*256) | (dst_local << 25)  -- byte offset of source row in
// bits [24:8] (one v_and to address), node-local id in [29:25].
__global__ __launch_bounds__(256) void scatter32(const int* __restrict__ src,
                                                 const int* __restrict__ dst,
                                                 const int* __restrict__ hstS,
                                                 int* __restrict__ esrt,
                                                 int E, int nbkt, int chunk) {
    __shared__ int cur[BKT_MAX];
    const int tid = threadIdx.x, blk = blockIdx.x;
    for (int i = tid; i < nbkt; i += 256) cur[i] = hstS[i * NSB + blk];
    __syncthreads();
    int s = blk * chunk, e = s + chunk; if (e > E) e = E;
    if ((((size_t)dst | (size_t)src) & 15) == 0) {
        int n4 = (e > s) ? ((e - s) >> 2) : 0;
        const intx4* d4p = (const intx4*)(dst + s);
        const intx4* s4p = (const intx4*)(src + s);
        for (int i = tid; i < n4; i += 256) {
            intx4 d4 = d4p[i];
            intx4 s4 = s4p[i];
#pragma unroll
            for (int k = 0; k < 4; k++) {
                int d = d4[k];
                int p = atomicAdd(&cur[d >> 5], 1);
                esrt[p] = (s4[k] << 8) | ((d & 31) << 25);
            }
        }
        for (int j = s + (n4 << 2) + tid; j < e; j += 256) {
            int d = dst[j];
            int p = atomicAdd(&cur[d >> 5], 1);
            esrt[p] = (src[j] << 8) | ((d & 31) << 25);
        }
    } else {
        for (int j = s + tid; j < e; j += 256) {
            int d = dst[j];
            int p = atomicAdd(&cur[d >> 5], 1);
            esrt[p] = (src[j] << 8) | ((d & 31) << 25);
        }
    }
}

// ---------------- bucketed aggregation: LDS sort + paired dwordx2 gather ----
// Per-CU gather-load service is ~25 cyc/instruction regardless of width
// (R1/R2/R4 all pinned at 24-26 cyc/load), so move 2 rows per instruction:
// lanes 0-31 load the even-slot edge's row, lanes 32-63 the odd-slot row
// (8B/lane). Edges are node-sorted, so a pair spans a node boundary rarely
// (~6%): common case accumulates both halves unconditionally (no exec-mask),
// rare case takes a scalar-branched predicated path. Keys readfirstlane'd ->
// all flush/branch control is SALU. Halves merge via shfl_xor(32) per NODE.
__global__ __launch_bounds__(256) void agg_bucket(const unsigned short* __restrict__ hb,
                                                  const int* __restrict__ hstS,
                                                  const int* __restrict__ esrt,
                                                  unsigned short* __restrict__ aggb,
                                                  int E, int nbkt, int n) {
    __shared__ int stage[CHUNK];
    __shared__ int sorted[CHUNK];
    __shared__ int cnt[32];
    __shared__ int coff[33];
    const int tid = threadIdx.x, lane = tid & 63, w = tid >> 6;
    const int b = blockIdx.x;

    const int p0 = hstS[b * NSB];
    const int p1 = (b + 1 < nbkt) ? hstS[(b + 1) * NSB] : E;

    if (p1 - p0 <= CHUNK) {
        // ---- sort chunk into LDS ----
        int m = p1 - p0;
        for (int i = tid; i < m; i += 256) stage[i] = esrt[p0 + i];
        if (tid < 32) cnt[tid] = 0;
        __syncthreads();
        for (int i = tid; i < m; i += 256) atomicAdd(&cnt[(stage[i] >> 25) & 31], 1);
        __syncthreads();
        if (tid < 32) {
            int v = cnt[tid];
            int x = v;
#pragma unroll
            for (int s = 1; s < 32; s <<= 1) {
                int y = __shfl_up(x, s);
                if (lane >= s) x += y;
            }
            coff[tid + 1] = x;
            if (tid == 0) coff[0] = 0;
            cnt[tid] = x - v;
        }
        __syncthreads();
        for (int i = tid; i < m; i += 256) {
            int pk = stage[i];
            int p = atomicAdd(&cnt[(pk >> 25) & 31], 1);
            sorted[p] = pk;
        }
        __syncthreads();

        // ---- paired gather ----
        const int w8 = w * 8;
        const int s = __builtin_amdgcn_readfirstlane(coff[w8]);
        const int e2 = __builtin_amdgcn_readfirstlane(coff[w8 + 8]);
        const char* hbB = (const char*)hb;
        const unsigned laneOff = (unsigned)(lane & 31) * 8u;
        const bool hiH = lane >= 32;
        floatx2 a01 = (floatx2)0.f, a23 = (floatx2)0.f;
        int curL = 0;

        auto flushTo = [&](int tgt) {
            while (curL < tgt) {
                float t0 = a01.x + __shfl_xor(a01.x, 32);
                float t1 = a01.y + __shfl_xor(a01.y, 32);
                float t2 = a23.x + __shfl_xor(a23.x, 32);
                float t3 = a23.y + __shfl_xor(a23.y, 32);
                int node = b * 32 + w8 + curL;
                int d = coff[w8 + curL + 1] - coff[w8 + curL];
                float inv = 1.0f / (float)(d > 1 ? d : 1);
                if (!hiH && node < n) {
                    uint2 o;
                    o.x = (unsigned int)f32_to_bf16_rne(t0 * inv)
                        | ((unsigned int)f32_to_bf16_rne(t1 * inv) << 16);
                    o.y = (unsigned int)f32_to_bf16_rne(t2 * inv)
                        | ((unsigned int)f32_to_bf16_rne(t3 * inv) << 16);
                    *(uint2*)((char*)aggb + (size_t)node * 256 + laneOff) = o;
                }
                a01 = (floatx2)0.f; a23 = (floatx2)0.f;
                ++curL;
            }
        };
        auto accum = [&](uint2 v) {
            floatx2 p0v = { __uint_as_float(v.x << 16), __uint_as_float(v.x & 0xffff0000u) };
            floatx2 p1v = { __uint_as_float(v.y << 16), __uint_as_float(v.y & 0xffff0000u) };
            a01 += p0v; a23 += p1v;
        };
        auto issueB = [&](uint2* v, int* ke, int* ko, int base) {
#pragma unroll
            for (int j = 0; j < 4; j++) {
                int kEv = sorted[base + 2 * j];
                int kOv = sorted[base + 2 * j + 1];
                ke[j] = __builtin_amdgcn_readfirstlane(kEv);
                ko[j] = __builtin_amdgcn_readfirstlane(kOv);
                int kSel = hiH ? kOv : kEv;
                unsigned off = (unsigned)(kSel & 0x01FFFF00) + laneOff;
                v[j] = *(const uint2*)(hbB + off);
            }
        };
        auto consumeB = [&](const uint2* v, const int* ke, const int* ko) {
#pragma unroll
            for (int j = 0; j < 4; j++) {
                int nE = (ke[j] >> 25) - w8;
                int nO = (ko[j] >> 25) - w8;
                if (nE == nO) {                 // scalar branch, ~94% of pairs
                    flushTo(nE);
                    accum(v[j]);
                } else {
                    flushTo(nE);
                    if (!hiH) accum(v[j]);
                    flushTo(nO);
                    if (hiH) accum(v[j]);
                }
            }
        };

        const int nb8 = (e2 - s) >> 3;
        uint2 vA[4], vB[4];
        int keA[4], koA[4], keB[4], koB[4];
        if (nb8 > 0) {
            issueB(vA, keA, koA, s);
            int k = 1;
            for (; k + 1 < nb8; k += 2) {
                issueB(vB, keB, koB, s + k * 8);
                consumeB(vA, keA, koA);
                issueB(vA, keA, koA, s + k * 8 + 8);
                consumeB(vB, keB, koB);
            }
            if (k < nb8) {
                issueB(vB, keB, koB, s + k * 8);
                consumeB(vA, keA, koA);
                consumeB(vB, keB, koB);
            } else {
                consumeB(vA, keA, koA);
            }
        }
        for (int i = s + (nb8 << 3); i < e2; i++) {
            int ks = __builtin_amdgcn_readfirstlane(sorted[i]);
            flushTo((ks >> 25) - w8);
            uint2 vv = *(const uint2*)(hbB + (unsigned)(ks & 0x01FFFF00) + laneOff);
            if (!hiH) accum(vv);            // only half0 counts (both halves loaded same row)
        }
        flushTo(8);
        return;
    }

    // ---- fallback: multi-chunk bucket ----
    float accx[8], accy[8];
    int dcnt[8];
#pragma unroll
    for (int nl = 0; nl < 8; nl++) { accx[nl] = 0.f; accy[nl] = 0.f; dcnt[nl] = 0; }
    for (int base = p0; base < p1; base += CHUNK) {
        int m = p1 - base; if (m > CHUNK) m = CHUNK;
        for (int i = tid; i < m; i += 256) stage[i] = esrt[base + i];
        if (tid < 32) cnt[tid] = 0;
        __syncthreads();
        for (int i = tid; i < m; i += 256) atomicAdd(&cnt[(stage[i] >> 25) & 31], 1);
        __syncthreads();
        if (tid < 32) {
            int v = cnt[tid];
            int x = v;
#pragma unroll
            for (int s = 1; s < 32; s <<= 1) {
                int y = __shfl_up(x, s);
                if (lane >= s) x += y;
            }
            coff[tid + 1] = x;
            if (tid == 0) coff[0] = 0;
            cnt[tid] = x - v;
        }
        __syncthreads();
        for (int i = tid; i < m; i += 256) {
            int pk = stage[i];
            int p = atomicAdd(&cnt[(pk >> 25) & 31], 1);
            sorted[p] = pk;
        }
        __syncthreads();
#pragma unroll
        for (int nl = 0; nl < 8; nl++) {
            int node_l = w * 8 + nl;
            int s = coff[node_l], e2 = coff[node_l + 1];
            dcnt[nl] += e2 - s;
            float ax = accx[nl], ay = accy[nl];
            int i = s;
            for (; i + 8 <= e2; i += 8) {
                unsigned int v[8];
#pragma unroll
                for (int j = 0; j < 8; j++) {
                    unsigned off = (unsigned)(sorted[i + j] & 0x01FFFF00);
                    v[j] = *(const unsigned int*)((const char*)hb + off + lane * 4);
                }
#pragma unroll
                for (int j = 0; j < 8; j++) {
                    ax += __uint_as_float(v[j] << 16);
                    ay += __uint_as_float(v[j] & 0xffff0000u);
                }
            }
            for (; i < e2; i++) {
                unsigned off = (unsigned)(sorted[i] & 0x01FFFF00);
                unsigned int vv = *(const unsigned int*)((const char*)hb + off + lane * 4);
                ax += __uint_as_float(vv << 16);
                ay += __uint_as_float(vv & 0xffff0000u);
            }
            accx[nl] = ax; accy[nl] = ay;
        }
        __syncthreads();
    }
#pragma unroll
    for (int nl = 0; nl < 8; nl++) {
        int node = b * 32 + w * 8 + nl;
        if (node < n) {
            int d = dcnt[nl];
            float inv = 1.0f / (float)(d > 1 ? d : 1);
            unsigned int o = (unsigned int)f32_to_bf16_rne(accx[nl] * inv)
                           | ((unsigned int)f32_to_bf16_rne(accy[nl] * inv) << 16);
            *(unsigned int*)(aggb + (size_t)node * 128 + lane * 2) = o;
        }
    }
}

// ---------------- fused SAGE update via split-bf16 MFMA ----------------
template <int LAYER, bool FINAL>
__global__ __launch_bounds__(256, 2) void update_mfma(
    const unsigned short* __restrict__ aggb, const void* __restrict__ hsrc,
    const uint4* __restrict__ Wsw, const float* __restrict__ bias,
    unsigned short* __restrict__ hout,
    const float* __restrict__ Wh, const float* __restrict__ bh,
    float* __restrict__ logits, int n) {
    __shared__ uint4 Alds[2048];
    __shared__ uint4 Wlds[2048];
    const int tid = threadIdx.x;
    const int lane = tid & 63;
    const int w = tid >> 6;
    const int i0 = blockIdx.x * 128;

    f32x4 acc[2][8];
#pragma unroll
    for (int mt = 0; mt < 2; mt++)
#pragma unroll
        for (int nt = 0; nt < 8; nt++) acc[mt][nt] = (f32x4)0.f;

    const int r = tid >> 1;
    const int half = tid & 1;
    const int rg = i0 + r;
    const bool inb = rg < n;
    const int mt_s = r >> 4;
    const int lidx = r & 15;

    for (int c = 0; c < 4; c++) {
        const bool haslo = (LAYER == 0 && c >= 2);
        {
            const uint4* srcW = Wsw + (size_t)c * 2048;
#pragma unroll
            for (int g = 0; g < 8; g++) Wlds[g * 256 + tid] = srcW[g * 256 + tid];
        }
        {
            unsigned short hiA[32], loA[32];
            if (LAYER == 0 && c >= 2) {
                const float4* s4 = (const float4*)((const float*)hsrc + (size_t)rg * 128 +
                                                   (c - 2) * 64 + half * 32);
#pragma unroll
                for (int q = 0; q < 8; q++) {
                    float4 f = inb ? s4[q] : make_float4(0.f, 0.f, 0.f, 0.f);
                    float vv[4] = {f.x, f.y, f.z, f.w};
#pragma unroll
                    for (int e = 0; e < 4; e++) {
                        unsigned short h = f32_to_bf16_rne(vv[e]);
                        hiA[q * 4 + e] = h;
                        loA[q * 4 + e] = f32_to_bf16_rne(vv[e] - bf16_bits_to_f32(h));
                    }
                }
            } else {
                const unsigned short* bsrc = (c < 2) ? aggb : (const unsigned short*)hsrc;
                int cc = (c < 2) ? c : c - 2;
                const uint4* s4 = (const uint4*)(bsrc + (size_t)rg * 128 + cc * 64 + half * 32);
#pragma unroll
                for (int q = 0; q < 4; q++) {
                    uint4 u = inb ? s4[q] : make_uint4(0, 0, 0, 0);
                    unsigned int uu[4] = {u.x, u.y, u.z, u.w};
#pragma unroll
                    for (int e = 0; e < 4; e++) {
                        hiA[q * 8 + e * 2 + 0] = (unsigned short)(uu[e] & 0xffffu);
                        hiA[q * 8 + e * 2 + 1] = (unsigned short)(uu[e] >> 16);
                    }
                }
            }
            unsigned int baseHi = ((mt_s * 2 + half) * 2 + 0) * 64;
#pragma unroll
            for (int g2 = 0; g2 < 4; g2++)
                Alds[baseHi + lidx + 16 * g2] = pack8(&hiA[g2 * 8]);
            if (haslo) {
#pragma unroll
                for (int g2 = 0; g2 < 4; g2++)
                    Alds[baseHi + 64 + lidx + 16 * g2] = pack8(&loA[g2 * 8]);
            }
        }
        __syncthreads();
#pragma unroll
        for (int kt = 0; kt < 2; kt++) {
            bf16x8 a0h = *(const bf16x8*)&Alds[(((w * 2 + 0) * 2 + kt) * 2 + 0) * 64 + lane];
            bf16x8 a1h = *(const bf16x8*)&Alds[(((w * 2 + 1) * 2 + kt) * 2 + 0) * 64 + lane];
            bf16x8 a0l, a1l;
            if (haslo) {
                a0l = *(const bf16x8*)&Alds[(((w * 2 + 0) * 2 + kt) * 2 + 1) * 64 + lane];
                a1l = *(const bf16x8*)&Alds[(((w * 2 + 1) * 2 + kt) * 2 + 1) * 64 + lane];
            }
#pragma unroll
            for (int nt = 0; nt < 8; nt++) {
                bf16x8 bhv = *(const bf16x8*)&Wlds[((kt * 8 + nt) * 2 + 0) * 64 + lane];
                bf16x8 blv = *(const bf16x8*)&Wlds[((kt * 8 + nt) * 2 + 1) * 64 + lane];
                acc[0][nt] = __builtin_amdgcn_mfma_f32_16x16x32_bf16(a0h, bhv, acc[0][nt], 0, 0, 0);
                acc[0][nt] = __builtin_amdgcn_mfma_f32_16x16x32_bf16(a0h, blv, acc[0][nt], 0, 0, 0);
                acc[1][nt] = __builtin_amdgcn_mfma_f32_16x16x32_bf16(a1h, bhv, acc[1][nt], 0, 0, 0);
                acc[1][nt] = __builtin_amdgcn_mfma_f32_16x16x32_bf16(a1h, blv, acc[1][nt], 0, 0, 0);
                if (haslo) {
                    acc[0][nt] = __builtin_amdgcn_mfma_f32_16x16x32_bf16(a0l, bhv, acc[0][nt], 0, 0, 0);
                    acc[1][nt] = __builtin_amdgcn_mfma_f32_16x16x32_bf16(a1l, bhv, acc[1][nt], 0, 0, 0);
                }
            }
        }
        __syncthreads();
    }

    const int col = lane & 15;
    const int g4 = lane >> 4;
    float bcol[8];
#pragma unroll
    for (int nt = 0; nt < 8; nt++) bcol[nt] = bias[nt * 16 + col];
    if (!FINAL) {
#pragma unroll
        for (int mt = 0; mt < 2; mt++) {
            int nodeBase = i0 + (w * 2 + mt) * 16 + g4 * 4;
#pragma unroll
            for (int reg = 0; reg < 4; reg++) {
                int node = nodeBase + reg;
                if (node < n) {
#pragma unroll
                    for (int nt = 0; nt < 8; nt++) {
                        float v = acc[mt][nt][reg] + bcol[nt];
                        v = v > 0.f ? v : 0.f;
                        hout[(size_t)node * 128 + nt * 16 + col] = f32_to_bf16_rne(v);
                    }
                }
            }
        }
    } else {
        float whc[8];
#pragma unroll
        for (int nt = 0; nt < 8; nt++) whc[nt] = Wh[nt * 16 + col];
        float bhv = bh[0];
#pragma unroll
        for (int mt = 0; mt < 2; mt++) {
            int nodeBase = i0 + (w * 2 + mt) * 16 + g4 * 4;
#pragma unroll
            for (int reg = 0; reg < 4; reg++) {
                float s = 0.f;
#pragma unroll
                for (int nt = 0; nt < 8; nt++) {
                    float v = acc[mt][nt][reg] + bcol[nt];
                    v = v > 0.f ? v : 0.f;
                    s += v * whc[nt];
                }
                s += __shfl_xor(s, 1);
                s += __shfl_xor(s, 2);
                s += __shfl_xor(s, 4);
                s += __shfl_xor(s, 8);
                int node = nodeBase + reg;
                if (col == 0 && node < n) logits[node] = s + bhv;
            }
        }
    }
}

extern "C" void kernel_launch(void* const* d_in, const int* in_sizes, int n_in,
                              void* d_out, int out_size, void* d_ws, size_t ws_size,
                              hipStream_t stream) {
    const float* x   = (const float*)d_in[0];
    const int*   ei  = (const int*)d_in[1];
    const float* Wn0 = (const float*)d_in[2];
    const float* Wr0 = (const float*)d_in[3];
    const float* b0  = (const float*)d_in[4];
    const float* Wn1 = (const float*)d_in[5];
    const float* Wr1 = (const float*)d_in[6];
    const float* b1  = (const float*)d_in[7];
    const float* Wh  = (const float*)d_in[8];
    const float* bh  = (const float*)d_in[9];
    float* logits = (float*)d_out;

    int N = in_sizes[0] / 128;
    int E = in_sizes[1] / 2;
    const int* src = ei;
    const int* dst = ei + E;

    int nbkt = (N + 31) >> 5;                       // 32-node coarse buckets
    int HS = nbkt * NSB;                            // histogram entries
    int NB = (HS + 2047) / 2048;                    // scan1 blocks
    int chunk = (((E + NSB - 1) / NSB) + 3) & ~3;   // multiple of 4 for int4 path

    char* ws = (char*)d_ws;
    size_t cur = 0;
    auto alloc = [&](size_t bytes) -> void* {
        void* p = ws + cur;
        cur += (bytes + 255) & ~(size_t)255;
        return p;
    };
    int* hist  = (int*)alloc((size_t)HS * 4);
    int* bsums = (int*)alloc((size_t)NB * 4);
    int* bbase = (int*)alloc((size_t)NB * 4);
    int* scrat = (int*)alloc(256);
    int* esrt  = (int*)alloc((size_t)E * 4);
    unsigned short* xb  = (unsigned short*)alloc((size_t)N * 128 * 2);
    unsigned short* h0b = (unsigned short*)alloc((size_t)N * 128 * 2);
    unsigned short* agb = (unsigned short*)alloc((size_t)N * 128 * 2);
    uint4* Wsw0 = (uint4*)alloc(131072);
    uint4* Wsw1 = (uint4*)alloc(131072);
    (void)ws_size; (void)n_in; (void)out_size;

    // fused prep: hist + weight swizzle + x->bf16 cvt (one launch)
    int n4 = N * 32;
    int gPrep = NSB + 32 + (n4 + 255) / 256;
    hipLaunchKernelGGL(prep, dim3(gPrep), dim3(256), 0, stream,
                       dst, hist, E, nbkt, chunk,
                       (const float4*)x, (ushort4*)xb, n4,
                       Wn0, Wr0, Wsw0, Wn1, Wr1, Wsw1);

    // scan chain + scatter
    hipLaunchKernelGGL(scan1_kernel,  dim3(NB),  dim3(256), 0, stream, hist, hist, bsums, HS);
    hipLaunchKernelGGL(scan2_wave,    dim3(1),   dim3(64),  0, stream, bsums, bbase, NB, scrat);
    hipLaunchKernelGGL(scan3b_kernel, dim3((HS + 255) / 256), dim3(256), 0, stream, hist, bbase, HS);
    hipLaunchKernelGGL(scatter32,     dim3(NSB), dim3(256), 0, stream, src, dst, hist, esrt, E, nbkt, chunk);

    int gUpd = (N + 127) / 128;

    // Layer 0
    hipLaunchKernelGGL(agg_bucket, dim3(nbkt), dim3(256), 0, stream, xb, hist, esrt, agb, E, nbkt, N);
    hipLaunchKernelGGL((update_mfma<0, false>), dim3(gUpd), dim3(256), 0, stream,
                       agb, (const void*)x, Wsw0, b0, h0b, nullptr, nullptr, nullptr, N);
    // Layer 1 + fused head
    hipLaunchKernelGGL(agg_bucket, dim3(nbkt), dim3(256), 0, stream, h0b, hist, esrt, agb, E, nbkt, N);
    hipLaunchKernelGGL((update_mfma<1, true>), dim3(gUpd), dim3(256), 0, stream,
                       agb, (const void*)h0b, Wsw1, b1, nullptr, Wh, bh, logits, N);
}